// Round 14
// baseline (817.123 us; speedup 1.0000x reference)
//
#include <hip/hip_runtime.h>
#include <hip/hip_fp16.h>

typedef _Float16 f16;
typedef __attribute__((ext_vector_type(8))) _Float16 f16x8;
typedef __attribute__((ext_vector_type(4))) _Float16 f16x4;
typedef __attribute__((ext_vector_type(4))) float f32x4;
typedef __attribute__((ext_vector_type(4))) float float4v;
typedef __attribute__((ext_vector_type(4))) int i32x4;

typedef __attribute__((address_space(3))) unsigned int lds_u32;
typedef const __attribute__((address_space(1))) unsigned int glb_u32;

// Shapes: x[512,256,256], carry0[256,256], Wi[256,768], bi[768],
//         Wh[256,768], bhn[256], Wo[256,16], bo[16] -> out[512,256,16] f32
//
// gx layout (scan-fragment order), f16, SCALED x128:
//   vecidx = ((t*16 + blk)*8 + w8)*6 + (gate*2 + nt2); elem = vecidx*256+lane*4+j
// Scan numerics (int8 MFMA, K=64): h int8 x127; Wh int8 x256; Wo int8 x16384;
// gx f16 as 128*(xWi+bi). All sigmoid/tanh args pre-scaled by +-log2e/128 so
// the transcendental is a bare v_exp_f32 (2^x).

#define CS 0.0039370079f        // 128/32512
#define CHEAD 4.805919e-7f      // 1/(127*16384)
#define FMAGIC 12582912.0f      // 1.5*2^23 (round-to-nearest-int trick)
#define IMAGIC 1262485504       // bit pattern of FMAGIC
#define CE  (-0.0112710550f)    // -log2e/128
#define C2E (0.0225421100f)     // +2*log2e/128
#define CSE  (-4.4374618e-5f)   // CS*CE
#define CSE2 (8.8749236e-5f)    // CS*C2E

static __device__ __forceinline__ float exp2_fast(float x) {
#if __has_builtin(__builtin_amdgcn_exp2f)
  return __builtin_amdgcn_exp2f(x);
#else
  return exp2f(x);
#endif
}

// ---------------- K0: tiled transpose Wi[256,768] -> WiT[768][256] f16 ------
__global__ void k_prep_wit(const float* __restrict__ Wi, f16* __restrict__ WiT) {
  __shared__ float tile[32][33];
  const int n0 = blockIdx.x * 32;
  const int k0 = blockIdx.y * 32;
  const int tx = threadIdx.x, ty = threadIdx.y;  // (32, 8)
#pragma unroll
  for (int i = 0; i < 4; ++i)
    tile[ty + i * 8][tx] = Wi[(size_t)(k0 + ty + i * 8) * 768 + n0 + tx];
  __syncthreads();
#pragma unroll
  for (int i = 0; i < 4; ++i)
    WiT[(size_t)(n0 + ty + i * 8) * 256 + k0 + tx] = (f16)tile[tx][ty + i * 8];
}

// ---------------- K0b: x f32 -> f16 (memory-bound pass) ---------------------
__global__ __launch_bounds__(256) void k_x16(const float* __restrict__ x,
                                             f16* __restrict__ x16) {
  size_t i = ((size_t)blockIdx.x * 256 + threadIdx.x) * 4;
  const size_t stride = (size_t)gridDim.x * 1024;
  for (; i < (size_t)512 * 256 * 256; i += stride) {
    float4v v = *reinterpret_cast<const float4v*>(x + i);
    f16x4 h;
    h[0] = (f16)v[0]; h[1] = (f16)v[1]; h[2] = (f16)v[2]; h[3] = (f16)v[3];
    *reinterpret_cast<f16x4*>(x16 + i) = h;
  }
}

// ---------------- K1 fast: gx = 128*(x16 @ Wi + bi), global_load_lds --------
__global__ __launch_bounds__(256, 4) void k_gemm_gx16(
    const f16* __restrict__ x16, const f16* __restrict__ WiT,
    const float* __restrict__ bi, f16* __restrict__ gx) {
  __shared__ f16 As[128 * 64];
  __shared__ f16 Bs[128 * 64];
  const int tid = threadIdx.x;
  const int lane = tid & 63;
  const int wave = tid >> 6;
  const int wm = wave >> 1, wn = wave & 1;
  const int m0 = blockIdx.y * 128;
  const int n0 = blockIdx.x * 128;

  const f16* aSrc[4];
  const f16* bSrc[4];
#pragma unroll
  for (int i = 0; i < 4; ++i) {
    const int s = (wave * 4 + i) * 64 + lane;
    const int row = s >> 3, cx = s & 7;
    const int g = cx ^ (row & 7);
    aSrc[i] = x16 + (size_t)(m0 + row) * 256 + g * 8;
    bSrc[i] = WiT + (size_t)(n0 + row) * 256 + g * 8;
  }

  f32x4 acc[4][4] = {};

  for (int ks = 0; ks < 4; ++ks) {
#pragma unroll
    for (int i = 0; i < 4; ++i) {
      __builtin_amdgcn_global_load_lds(
          (glb_u32*)(aSrc[i] + ks * 64),
          (lds_u32*)(reinterpret_cast<char*>(As) + (wave * 4 + i) * 1024), 16, 0, 0);
      __builtin_amdgcn_global_load_lds(
          (glb_u32*)(bSrc[i] + ks * 64),
          (lds_u32*)(reinterpret_cast<char*>(Bs) + (wave * 4 + i) * 1024), 16, 0, 0);
    }
    asm volatile("s_waitcnt vmcnt(0)" ::: "memory");
    __syncthreads();
#pragma unroll
    for (int kt = 0; kt < 2; ++kt) {
      const int kb = kt * 64 + ((lane >> 4) << 4);
      f16x8 a[4], b[4];
#pragma unroll
      for (int mt = 0; mt < 4; ++mt) {
        int r = wm * 64 + mt * 16 + (lane & 15);
        a[mt] = *reinterpret_cast<const f16x8*>(
            reinterpret_cast<const char*>(As) + r * 128 + (kb ^ ((r & 7) << 4)));
      }
#pragma unroll
      for (int nt = 0; nt < 4; ++nt) {
        int r = wn * 64 + nt * 16 + (lane & 15);
        b[nt] = *reinterpret_cast<const f16x8*>(
            reinterpret_cast<const char*>(Bs) + r * 128 + (kb ^ ((r & 7) << 4)));
      }
#pragma unroll
      for (int mt = 0; mt < 4; ++mt)
#pragma unroll
        for (int nt = 0; nt < 4; ++nt)
          acc[mt][nt] = __builtin_amdgcn_mfma_f32_16x16x32_f16(
              a[mt], b[nt], acc[mt][nt], 0, 0, 0);
    }
    __syncthreads();
  }
  const int t_  = blockIdx.y >> 1;
  const int bhf = blockIdx.y & 1;
  const int gg  = blockIdx.x >> 1;
  const int xh  = blockIdx.x & 1;
  float biv[4];
#pragma unroll
  for (int nt = 0; nt < 4; ++nt) biv[nt] = bi[n0 + wn * 64 + nt * 16 + (lane & 15)];
#pragma unroll
  for (int mt = 0; mt < 4; ++mt) {
    const int blk = bhf * 8 + wm * 4 + mt;
#pragma unroll
    for (int nt = 0; nt < 4; ++nt) {
      const int w = xh * 4 + wn * 2 + (nt >> 1);
      const int vecidx = ((t_ * 16 + blk) * 8 + w) * 6 + gg * 2 + (nt & 1);
      f16x4 hv;
#pragma unroll
      for (int r = 0; r < 4; ++r)
        hv[r] = (f16)((acc[mt][nt][r] + biv[nt]) * 128.0f);
      *reinterpret_cast<f16x4*>(gx + (size_t)vecidx * 256 + lane * 4) = hv;
    }
  }
}

// ---------------- K1 fallback: gx from f32 x --------------------------------
__global__ __launch_bounds__(256, 4) void k_gemm_gx(
    const float* __restrict__ x, const f16* __restrict__ WiT,
    const float* __restrict__ bi, f16* __restrict__ gx) {
  __shared__ f16 As[128 * 64];
  __shared__ f16 Bs[128 * 64];
  const int tid = threadIdx.x;
  const int lane = tid & 63;
  const int wave = tid >> 6;
  const int wm = wave >> 1, wn = wave & 1;
  const int m0 = blockIdx.y * 128;
  const int n0 = blockIdx.x * 128;

  f32x4 acc[4][4] = {};

  for (int ks = 0; ks < 4; ++ks) {
    const int k0 = ks * 64;
#pragma unroll
    for (int i = 0; i < 8; ++i) {
      int c = i * 256 + tid;
      int row = c >> 4, cx = c & 15;
      float4v v = *reinterpret_cast<const float4v*>(
          x + (size_t)(m0 + row) * 256 + k0 + cx * 4);
      f16x4 hv;
      hv[0] = (f16)v[0]; hv[1] = (f16)v[1]; hv[2] = (f16)v[2]; hv[3] = (f16)v[3];
      int boff = row * 128 + ((cx * 8) ^ ((row & 7) << 4));
      *reinterpret_cast<f16x4*>(reinterpret_cast<char*>(As) + boff) = hv;
    }
#pragma unroll
    for (int i = 0; i < 4; ++i) {
      int c = i * 256 + tid;
      int n = c >> 3, cx = c & 7;
      f16x8 v = *reinterpret_cast<const f16x8*>(
          WiT + (size_t)(n0 + n) * 256 + k0 + cx * 8);
      int boff = n * 128 + ((cx * 16) ^ ((n & 7) << 4));
      *reinterpret_cast<f16x8*>(reinterpret_cast<char*>(Bs) + boff) = v;
    }
    __syncthreads();
#pragma unroll
    for (int kt = 0; kt < 2; ++kt) {
      const int kb = kt * 64 + ((lane >> 4) << 4);
      f16x8 a[4], b[4];
#pragma unroll
      for (int mt = 0; mt < 4; ++mt) {
        int r = wm * 64 + mt * 16 + (lane & 15);
        a[mt] = *reinterpret_cast<const f16x8*>(
            reinterpret_cast<const char*>(As) + r * 128 + (kb ^ ((r & 7) << 4)));
      }
#pragma unroll
      for (int nt = 0; nt < 4; ++nt) {
        int r = wn * 64 + nt * 16 + (lane & 15);
        b[nt] = *reinterpret_cast<const f16x8*>(
            reinterpret_cast<const char*>(Bs) + r * 128 + (kb ^ ((r & 7) << 4)));
      }
#pragma unroll
      for (int mt = 0; mt < 4; ++mt)
#pragma unroll
        for (int nt = 0; nt < 4; ++nt)
          acc[mt][nt] = __builtin_amdgcn_mfma_f32_16x16x32_f16(
              a[mt], b[nt], acc[mt][nt], 0, 0, 0);
    }
    __syncthreads();
  }
  const int t_  = blockIdx.y >> 1;
  const int bhf = blockIdx.y & 1;
  const int gg  = blockIdx.x >> 1;
  const int xh  = blockIdx.x & 1;
  float biv[4];
#pragma unroll
  for (int nt = 0; nt < 4; ++nt) biv[nt] = bi[n0 + wn * 64 + nt * 16 + (lane & 15)];
#pragma unroll
  for (int mt = 0; mt < 4; ++mt) {
    const int blk = bhf * 8 + wm * 4 + mt;
#pragma unroll
    for (int nt = 0; nt < 4; ++nt) {
      const int w = xh * 4 + wn * 2 + (nt >> 1);
      const int vecidx = ((t_ * 16 + blk) * 8 + w) * 6 + gg * 2 + (nt & 1);
      f16x4 hv;
#pragma unroll
      for (int r = 0; r < 4; ++r)
        hv[r] = (f16)((acc[mt][nt][r] + biv[nt]) * 128.0f);
      *reinterpret_cast<f16x4*>(gx + (size_t)vecidx * 256 + lane * 4) = hv;
    }
  }
}

// ---------------- K2: int8 GRU scan, gate-major + distributed head ----------
// 16 blocks x 16 waves (4/SIMD). Wave owns 16 H-cols; Wh int8 B-frags in
// VGPRs. h int8 A-frags in 8-slot LDS ring. Gate-major MFMA chains let
// rg/zg transcendentals overlap the n-chain on the matrix pipe; gv cvt+scale
// runs in the MFMA shadow; head distributed one wave per step (no batch
// barrier). exp args pre-scaled so v_exp_f32 is bare.
__global__ __launch_bounds__(1024) void k_scan(
    const float* __restrict__ carry0, const float* __restrict__ Wh,
    const float* __restrict__ bhn, const f16* __restrict__ gxL,
    const float* __restrict__ Wo, const float* __restrict__ bo,
    float* __restrict__ out) {
  __shared__ __align__(16) char ha[8 * 4096];   // 32 KB: h ring, 8 slots
  __shared__ __align__(16) char wofs[4 * 1024]; // 4 KB: Wo int8 B-frags
  const int tid = threadIdx.x;
  const int lane = tid & 63;
  const int wave = tid >> 6;  // 0..15
  const int l15 = lane & 15, l4 = lane >> 4;
  const int r0 = blockIdx.x * 16;

  i32x4 whq[3][4];
#pragma unroll
  for (int g = 0; g < 3; ++g) {
    const int col = g * 256 + wave * 16 + l15;
#pragma unroll
    for (int kt = 0; kt < 4; ++kt) {
      int wd[4];
#pragma unroll
      for (int w = 0; w < 4; ++w) {
        int b = 0;
#pragma unroll
        for (int by = 0; by < 4; ++by) {
          const int e = w * 4 + by;
          int q = (int)rintf(Wh[(size_t)(kt * 64 + l4 * 16 + e) * 768 + col] *
                             256.0f);
          b |= (q & 255) << (8 * by);
        }
        wd[w] = b;
      }
      whq[g][kt] = (i32x4){wd[0], wd[1], wd[2], wd[3]};
    }
  }
  if (wave < 4) {
    int wd[4];
#pragma unroll
    for (int w = 0; w < 4; ++w) {
      int b = 0;
#pragma unroll
      for (int by = 0; by < 4; ++by) {
        const int e = w * 4 + by;
        int q = (int)rintf(Wo[(wave * 64 + l4 * 16 + e) * 16 + l15] * 16384.0f);
        b |= (q & 255) << (8 * by);
      }
      wd[w] = b;
    }
    *reinterpret_cast<i32x4*>(wofs + wave * 1024 + lane * 16) =
        (i32x4){wd[0], wd[1], wd[2], wd[3]};
  }
  const float bhE = 128.0f * C2E * bhn[wave * 16 + l15];  // pre-scaled n bias
  const float bov = bo[l15];

  const int wrbase = (wave >> 2) * 1024 + ((wave & 3) * 16 + l4 * 4) * 16 + l15;

  float hcur[4];
#pragma unroll
  for (int j = 0; j < 4; ++j) {
    float h = carry0[(size_t)(r0 + l4 * 4 + j) * 256 + wave * 16 + l15];
    hcur[j] = h;
    float m = fmaf(h, 127.0f, FMAGIC);
    int hq = __builtin_bit_cast(int, m) - IMAGIC;
    ha[wrbase + j * 16] = (char)hq;
  }
  __syncthreads();

  const f16* gp0 = gxL + (((size_t)blockIdx.x * 8 + (wave >> 1)) * 6 +
                          (size_t)(wave & 1)) * 256 + (size_t)lane * 4;

  auto head_tau = [&](int tau) {
    const int sbase = (tau & 7) * 4096;
    i32x4 aco = {};
#pragma unroll
    for (int kt = 0; kt < 4; ++kt) {
      i32x4 ah = *reinterpret_cast<const i32x4*>(ha + sbase + kt * 1024 + lane * 16);
      i32x4 wb = *reinterpret_cast<const i32x4*>(wofs + kt * 1024 + lane * 16);
      aco = __builtin_amdgcn_mfma_i32_16x16x64_i8(ah, wb, aco, 0, 0, 0);
    }
#pragma unroll
    for (int r = 0; r < 4; ++r) {
      float y = fmaf((float)aco[r], CHEAD, bov);
      if (l15 >= 8) y = __expf(fminf(fmaxf(y, -20.0f), 2.0f));
      out[((size_t)(tau - 1) * 256 + r0 + l4 * 4 + r) * 16 + l15] = y;
    }
  };

  f16x4 gva[3], gvb[3];
#pragma unroll
  for (int g = 0; g < 3; ++g)
    gva[g] = *reinterpret_cast<const f16x4*>(gp0 + g * 512);

  auto step = [&](int cur, int nxt, f16x4 (&gv)[3], f16x4 (&gvn)[3],
                  const f16* gpn, int tt) {
    // prefetch NEXT step's gx (in flight across the light barrier)
#pragma unroll
    for (int g = 0; g < 3; ++g)
      gvn[g] = *reinterpret_cast<const f16x4*>(gpn + g * 512);

    // convert+pre-scale current gv (VALU work in the MFMA-issue shadow)
    float g0e[4], g1e[4], g2e[4];
#pragma unroll
    for (int j = 0; j < 4; ++j) {
      g0e[j] = (float)gv[0][j] * CE;
      g1e[j] = (float)gv[1][j] * CE;
      g2e[j] = (float)gv[2][j] * C2E;
    }

    // h A-frags once, then gate-major chains: acc0 ready after 4 MFMAs
    i32x4 a0 = *reinterpret_cast<const i32x4*>(ha + cur + 0 * 1024 + lane * 16);
    i32x4 a1 = *reinterpret_cast<const i32x4*>(ha + cur + 1 * 1024 + lane * 16);
    i32x4 a2 = *reinterpret_cast<const i32x4*>(ha + cur + 2 * 1024 + lane * 16);
    i32x4 a3 = *reinterpret_cast<const i32x4*>(ha + cur + 3 * 1024 + lane * 16);
    i32x4 acc0 = {}, acc1 = {}, acc2 = {};
    acc0 = __builtin_amdgcn_mfma_i32_16x16x64_i8(a0, whq[0][0], acc0, 0, 0, 0);
    acc0 = __builtin_amdgcn_mfma_i32_16x16x64_i8(a1, whq[0][1], acc0, 0, 0, 0);
    acc0 = __builtin_amdgcn_mfma_i32_16x16x64_i8(a2, whq[0][2], acc0, 0, 0, 0);
    acc0 = __builtin_amdgcn_mfma_i32_16x16x64_i8(a3, whq[0][3], acc0, 0, 0, 0);
    acc1 = __builtin_amdgcn_mfma_i32_16x16x64_i8(a0, whq[1][0], acc1, 0, 0, 0);
    acc1 = __builtin_amdgcn_mfma_i32_16x16x64_i8(a1, whq[1][1], acc1, 0, 0, 0);
    acc1 = __builtin_amdgcn_mfma_i32_16x16x64_i8(a2, whq[1][2], acc1, 0, 0, 0);
    acc1 = __builtin_amdgcn_mfma_i32_16x16x64_i8(a3, whq[1][3], acc1, 0, 0, 0);
    acc2 = __builtin_amdgcn_mfma_i32_16x16x64_i8(a0, whq[2][0], acc2, 0, 0, 0);
    acc2 = __builtin_amdgcn_mfma_i32_16x16x64_i8(a1, whq[2][1], acc2, 0, 0, 0);
    acc2 = __builtin_amdgcn_mfma_i32_16x16x64_i8(a2, whq[2][2], acc2, 0, 0, 0);
    acc2 = __builtin_amdgcn_mfma_i32_16x16x64_i8(a3, whq[2][3], acc2, 0, 0, 0);

    // r/z gates early (overlap the n-chain + other waves' MFMAs)
    float rg[4], zg[4];
#pragma unroll
    for (int j = 0; j < 4; ++j) {
      float ar = fmaf((float)acc0[j], CSE, g0e[j]);
      rg[j] = __builtin_amdgcn_rcpf(1.0f + exp2_fast(ar));
      float az = fmaf((float)acc1[j], CSE, g1e[j]);
      zg[j] = __builtin_amdgcn_rcpf(1.0f + exp2_fast(az));
    }

    // distributed head: wave (tt&15) emits out[tt-1] from ring slot tt&7
    if (tt > 0 && wave == (tt & 15)) head_tau(tt);

    // n gate + h update + int8 A-frag write of h_{t+1}
#pragma unroll
    for (int j = 0; j < 4; ++j) {
      float pe = fmaf((float)acc2[j], CSE2, bhE);
      float an = fmaf(rg[j], pe, g2e[j]);
      float ng = fmaf(-2.0f, __builtin_amdgcn_rcpf(1.0f + exp2_fast(an)), 1.0f);
      float h = fmaf(zg[j], hcur[j] - ng, ng);
      hcur[j] = h;
      float m = fmaf(h, 127.0f, FMAGIC);
      int hq = __builtin_bit_cast(int, m) - IMAGIC;
      ha[nxt + wrbase + j * 16] = (char)hq;
    }
    // light barrier: order LDS h-handoff only (vmcnt stays in flight)
    asm volatile("s_waitcnt lgkmcnt(0)\n\ts_barrier" ::: "memory");
  };

  for (int t = 0; t < 512; t += 2) {
    const f16* gp1 = gp0 + (size_t)(t + 1) * 196608;
    const f16* gp2 = gp0 + (size_t)(t + 2 <= 511 ? t + 2 : 511) * 196608;
    step((t & 7) * 4096, ((t + 1) & 7) * 4096, gva, gvb, gp1, t);
    step(((t + 1) & 7) * 4096, ((t + 2) & 7) * 4096, gvb, gva, gp2, t + 1);
  }

  // final head: out[511] = h_512 @ Wo (slot 0)
  if (wave == 0) head_tau(512);
}

extern "C" void kernel_launch(void* const* d_in, const int* in_sizes, int n_in,
                              void* d_out, int out_size, void* d_ws, size_t ws_size,
                              hipStream_t stream) {
  const float* x      = (const float*)d_in[0];
  const float* carry0 = (const float*)d_in[1];
  const float* Wi     = (const float*)d_in[2];
  const float* bi     = (const float*)d_in[3];
  const float* Wh     = (const float*)d_in[4];
  const float* bhn    = (const float*)d_in[5];
  const float* Wo     = (const float*)d_in[6];
  const float* bo     = (const float*)d_in[7];
  float* out = (float*)d_out;

  f16* gx  = (f16*)d_ws;                        // 512*256*768 f16 = 192 MiB
  f16* WiT = gx + (size_t)512 * 256 * 768;      // 768*256 f16 = 384 KiB
  f16* xh  = WiT + (size_t)768 * 256;           // 512*256*256 f16 = 64 MiB

  const size_t need = ((size_t)512 * 256 * 768 + (size_t)768 * 256 +
                       (size_t)512 * 256 * 256) * sizeof(f16);

  k_prep_wit<<<dim3(24, 8), dim3(32, 8), 0, stream>>>(Wi, WiT);
  if (ws_size >= need) {
    k_x16<<<dim3(2048), dim3(256), 0, stream>>>(x, xh);
    k_gemm_gx16<<<dim3(6, 1024), dim3(256), 0, stream>>>(xh, WiT, bi, gx);
  } else {
    k_gemm_gx<<<dim3(6, 1024), dim3(256), 0, stream>>>(x, WiT, bi, gx);
  }
  k_scan<<<dim3(16), dim3(1024), 0, stream>>>(carry0, Wh, bhn, gx, Wo, bo, out);
}

// Round 15
// 814.921 us; speedup vs baseline: 1.0027x; 1.0027x over previous
//
#include <hip/hip_runtime.h>
#include <hip/hip_fp16.h>

typedef _Float16 f16;
typedef __attribute__((ext_vector_type(8))) _Float16 f16x8;
typedef __attribute__((ext_vector_type(4))) _Float16 f16x4;
typedef __attribute__((ext_vector_type(4))) float f32x4;
typedef __attribute__((ext_vector_type(4))) float float4v;
typedef __attribute__((ext_vector_type(4))) int i32x4;

typedef __attribute__((address_space(3))) unsigned int lds_u32;
typedef const __attribute__((address_space(1))) unsigned int glb_u32;

// Shapes: x[512,256,256], carry0[256,256], Wi[256,768], bi[768],
//         Wh[256,768], bhn[256], Wo[256,16], bo[16] -> out[512,256,16] f32
//
// gx layout (scan-fragment order), f16, SCALED x128:
//   vecidx = ((t*16 + blk)*8 + w8)*6 + (gate*2 + nt2); elem = vecidx*256+lane*4+j
// Scan numerics (int8 MFMA, K=64): h int8 x127; Wh int8 x256; Wo int8 x16384;
// gx f16 as 128*(xWi+bi). preact*128 = gx + acc*CS; head y = acc*CHEAD.
//
// R15: scan batch-split x2 (32 blocks x 8 rows). MFMA per SIMD unchanged
// (M=16 tiles, rows 8-15 zero); elementwise confined to lanes l4<2 to test
// whether the SIMD32 skips a fully-masked 32-lane half-pass. kt-major MFMA
// order restored (R14's gate-major chains stalled on acc dependencies).

#define CS 0.0039370079f        // 128/32512
#define CHEAD 4.805919e-7f      // 1/(127*16384)
#define FMAGIC 12582912.0f      // 1.5*2^23 (round-to-nearest-int trick)
#define IMAGIC 1262485504       // bit pattern of FMAGIC

static __device__ __forceinline__ float sigm_s(float x) {  // sigmoid(x/128)
  return __builtin_amdgcn_rcpf(1.0f + __expf(-0.0078125f * x));
}
static __device__ __forceinline__ float tanh_s(float x) {  // tanh(x/128)
  float e = __expf(0.015625f * x);
  return 1.0f - 2.0f * __builtin_amdgcn_rcpf(e + 1.0f);
}

// ---------------- K0: tiled transpose Wi[256,768] -> WiT[768][256] f16 ------
__global__ void k_prep_wit(const float* __restrict__ Wi, f16* __restrict__ WiT) {
  __shared__ float tile[32][33];
  const int n0 = blockIdx.x * 32;
  const int k0 = blockIdx.y * 32;
  const int tx = threadIdx.x, ty = threadIdx.y;  // (32, 8)
#pragma unroll
  for (int i = 0; i < 4; ++i)
    tile[ty + i * 8][tx] = Wi[(size_t)(k0 + ty + i * 8) * 768 + n0 + tx];
  __syncthreads();
#pragma unroll
  for (int i = 0; i < 4; ++i)
    WiT[(size_t)(n0 + ty + i * 8) * 256 + k0 + tx] = (f16)tile[tx][ty + i * 8];
}

// ---------------- K0b: x f32 -> f16 (memory-bound pass) ---------------------
__global__ __launch_bounds__(256) void k_x16(const float* __restrict__ x,
                                             f16* __restrict__ x16) {
  size_t i = ((size_t)blockIdx.x * 256 + threadIdx.x) * 4;
  const size_t stride = (size_t)gridDim.x * 1024;
  for (; i < (size_t)512 * 256 * 256; i += stride) {
    float4v v = *reinterpret_cast<const float4v*>(x + i);
    f16x4 h;
    h[0] = (f16)v[0]; h[1] = (f16)v[1]; h[2] = (f16)v[2]; h[3] = (f16)v[3];
    *reinterpret_cast<f16x4*>(x16 + i) = h;
  }
}

// ---------------- K1 fast: gx = 128*(x16 @ Wi + bi), global_load_lds --------
__global__ __launch_bounds__(256, 4) void k_gemm_gx16(
    const f16* __restrict__ x16, const f16* __restrict__ WiT,
    const float* __restrict__ bi, f16* __restrict__ gx) {
  __shared__ f16 As[128 * 64];
  __shared__ f16 Bs[128 * 64];
  const int tid = threadIdx.x;
  const int lane = tid & 63;
  const int wave = tid >> 6;
  const int wm = wave >> 1, wn = wave & 1;
  const int m0 = blockIdx.y * 128;
  const int n0 = blockIdx.x * 128;

  const f16* aSrc[4];
  const f16* bSrc[4];
#pragma unroll
  for (int i = 0; i < 4; ++i) {
    const int s = (wave * 4 + i) * 64 + lane;
    const int row = s >> 3, cx = s & 7;
    const int g = cx ^ (row & 7);
    aSrc[i] = x16 + (size_t)(m0 + row) * 256 + g * 8;
    bSrc[i] = WiT + (size_t)(n0 + row) * 256 + g * 8;
  }

  f32x4 acc[4][4] = {};

  for (int ks = 0; ks < 4; ++ks) {
#pragma unroll
    for (int i = 0; i < 4; ++i) {
      __builtin_amdgcn_global_load_lds(
          (glb_u32*)(aSrc[i] + ks * 64),
          (lds_u32*)(reinterpret_cast<char*>(As) + (wave * 4 + i) * 1024), 16, 0, 0);
      __builtin_amdgcn_global_load_lds(
          (glb_u32*)(bSrc[i] + ks * 64),
          (lds_u32*)(reinterpret_cast<char*>(Bs) + (wave * 4 + i) * 1024), 16, 0, 0);
    }
    asm volatile("s_waitcnt vmcnt(0)" ::: "memory");
    __syncthreads();
#pragma unroll
    for (int kt = 0; kt < 2; ++kt) {
      const int kb = kt * 64 + ((lane >> 4) << 4);
      f16x8 a[4], b[4];
#pragma unroll
      for (int mt = 0; mt < 4; ++mt) {
        int r = wm * 64 + mt * 16 + (lane & 15);
        a[mt] = *reinterpret_cast<const f16x8*>(
            reinterpret_cast<const char*>(As) + r * 128 + (kb ^ ((r & 7) << 4)));
      }
#pragma unroll
      for (int nt = 0; nt < 4; ++nt) {
        int r = wn * 64 + nt * 16 + (lane & 15);
        b[nt] = *reinterpret_cast<const f16x8*>(
            reinterpret_cast<const char*>(Bs) + r * 128 + (kb ^ ((r & 7) << 4)));
      }
#pragma unroll
      for (int mt = 0; mt < 4; ++mt)
#pragma unroll
        for (int nt = 0; nt < 4; ++nt)
          acc[mt][nt] = __builtin_amdgcn_mfma_f32_16x16x32_f16(
              a[mt], b[nt], acc[mt][nt], 0, 0, 0);
    }
    __syncthreads();
  }
  const int t_  = blockIdx.y >> 1;
  const int bhf = blockIdx.y & 1;
  const int gg  = blockIdx.x >> 1;
  const int xh  = blockIdx.x & 1;
  float biv[4];
#pragma unroll
  for (int nt = 0; nt < 4; ++nt) biv[nt] = bi[n0 + wn * 64 + nt * 16 + (lane & 15)];
#pragma unroll
  for (int mt = 0; mt < 4; ++mt) {
    const int blk = bhf * 8 + wm * 4 + mt;
#pragma unroll
    for (int nt = 0; nt < 4; ++nt) {
      const int w = xh * 4 + wn * 2 + (nt >> 1);
      const int vecidx = ((t_ * 16 + blk) * 8 + w) * 6 + gg * 2 + (nt & 1);
      f16x4 hv;
#pragma unroll
      for (int r = 0; r < 4; ++r)
        hv[r] = (f16)((acc[mt][nt][r] + biv[nt]) * 128.0f);
      *reinterpret_cast<f16x4*>(gx + (size_t)vecidx * 256 + lane * 4) = hv;
    }
  }
}

// ---------------- K1 fallback: gx from f32 x --------------------------------
__global__ __launch_bounds__(256, 4) void k_gemm_gx(
    const float* __restrict__ x, const f16* __restrict__ WiT,
    const float* __restrict__ bi, f16* __restrict__ gx) {
  __shared__ f16 As[128 * 64];
  __shared__ f16 Bs[128 * 64];
  const int tid = threadIdx.x;
  const int lane = tid & 63;
  const int wave = tid >> 6;
  const int wm = wave >> 1, wn = wave & 1;
  const int m0 = blockIdx.y * 128;
  const int n0 = blockIdx.x * 128;

  f32x4 acc[4][4] = {};

  for (int ks = 0; ks < 4; ++ks) {
    const int k0 = ks * 64;
#pragma unroll
    for (int i = 0; i < 8; ++i) {
      int c = i * 256 + tid;
      int row = c >> 4, cx = c & 15;
      float4v v = *reinterpret_cast<const float4v*>(
          x + (size_t)(m0 + row) * 256 + k0 + cx * 4);
      f16x4 hv;
      hv[0] = (f16)v[0]; hv[1] = (f16)v[1]; hv[2] = (f16)v[2]; hv[3] = (f16)v[3];
      int boff = row * 128 + ((cx * 8) ^ ((row & 7) << 4));
      *reinterpret_cast<f16x4*>(reinterpret_cast<char*>(As) + boff) = hv;
    }
#pragma unroll
    for (int i = 0; i < 4; ++i) {
      int c = i * 256 + tid;
      int n = c >> 3, cx = c & 7;
      f16x8 v = *reinterpret_cast<const f16x8*>(
          WiT + (size_t)(n0 + n) * 256 + k0 + cx * 8);
      int boff = n * 128 + ((cx * 16) ^ ((n & 7) << 4));
      *reinterpret_cast<f16x8*>(reinterpret_cast<char*>(Bs) + boff) = v;
    }
    __syncthreads();
#pragma unroll
    for (int kt = 0; kt < 2; ++kt) {
      const int kb = kt * 64 + ((lane >> 4) << 4);
      f16x8 a[4], b[4];
#pragma unroll
      for (int mt = 0; mt < 4; ++mt) {
        int r = wm * 64 + mt * 16 + (lane & 15);
        a[mt] = *reinterpret_cast<const f16x8*>(
            reinterpret_cast<const char*>(As) + r * 128 + (kb ^ ((r & 7) << 4)));
      }
#pragma unroll
      for (int nt = 0; nt < 4; ++nt) {
        int r = wn * 64 + nt * 16 + (lane & 15);
        b[nt] = *reinterpret_cast<const f16x8*>(
            reinterpret_cast<const char*>(Bs) + r * 128 + (kb ^ ((r & 7) << 4)));
      }
#pragma unroll
      for (int mt = 0; mt < 4; ++mt)
#pragma unroll
        for (int nt = 0; nt < 4; ++nt)
          acc[mt][nt] = __builtin_amdgcn_mfma_f32_16x16x32_f16(
              a[mt], b[nt], acc[mt][nt], 0, 0, 0);
    }
    __syncthreads();
  }
  const int t_  = blockIdx.y >> 1;
  const int bhf = blockIdx.y & 1;
  const int gg  = blockIdx.x >> 1;
  const int xh  = blockIdx.x & 1;
  float biv[4];
#pragma unroll
  for (int nt = 0; nt < 4; ++nt) biv[nt] = bi[n0 + wn * 64 + nt * 16 + (lane & 15)];
#pragma unroll
  for (int mt = 0; mt < 4; ++mt) {
    const int blk = bhf * 8 + wm * 4 + mt;
#pragma unroll
    for (int nt = 0; nt < 4; ++nt) {
      const int w = xh * 4 + wn * 2 + (nt >> 1);
      const int vecidx = ((t_ * 16 + blk) * 8 + w) * 6 + gg * 2 + (nt & 1);
      f16x4 hv;
#pragma unroll
      for (int r = 0; r < 4; ++r)
        hv[r] = (f16)((acc[mt][nt][r] + biv[nt]) * 128.0f);
      *reinterpret_cast<f16x4*>(gx + (size_t)vecidx * 256 + lane * 4) = hv;
    }
  }
}

// ---------------- K2: int8 GRU scan, 32 blocks x 8 rows (R13 core) ----------
// Block (blk = bid>>1, half = bid&1) owns batch rows blk*16 + half*8 .. +7.
// MFMA tiles stay M=16 with rows 8-15 held at zero (masked lanes write 0
// every step). Elementwise confined to lanes l4<2. LDS padded >80KB to
// force 1 block/CU. kt-major MFMA interleave (dep distance 3).
__global__ __launch_bounds__(1024) void k_scan(
    const float* __restrict__ carry0, const float* __restrict__ Wh,
    const float* __restrict__ bhn, const f16* __restrict__ gxL,
    const float* __restrict__ Wo, const float* __restrict__ bo,
    float* __restrict__ out) {
  __shared__ __align__(16) char ha[8 * 4096];   // 32 KB: h ring, 8 slots
  __shared__ __align__(16) char wofs[4 * 1024]; // 4 KB: Wo int8 B-frags
  __shared__ char occ_pad[49152];               // force 1 block/CU (86 KB total)
  const int tid = threadIdx.x;
  const int lane = tid & 63;
  const int wave = tid >> 6;  // 0..15
  const int l15 = lane & 15, l4 = lane >> 4;
  const int blk = blockIdx.x >> 1;
  const int half = blockIdx.x & 1;
  const int r0 = blk * 16 + half * 8;  // 8 batch rows
  if (bhn[0] > 1e30f) occ_pad[tid] = 1;  // never true; keeps occ_pad allocated

  i32x4 whq[3][4];
#pragma unroll
  for (int g = 0; g < 3; ++g) {
    const int col = g * 256 + wave * 16 + l15;
#pragma unroll
    for (int kt = 0; kt < 4; ++kt) {
      int wd[4];
#pragma unroll
      for (int w = 0; w < 4; ++w) {
        int b = 0;
#pragma unroll
        for (int by = 0; by < 4; ++by) {
          const int e = w * 4 + by;
          int q = (int)rintf(Wh[(size_t)(kt * 64 + l4 * 16 + e) * 768 + col] *
                             256.0f);
          b |= (q & 255) << (8 * by);
        }
        wd[w] = b;
      }
      whq[g][kt] = (i32x4){wd[0], wd[1], wd[2], wd[3]};
    }
  }
  if (wave < 4) {
    int wd[4];
#pragma unroll
    for (int w = 0; w < 4; ++w) {
      int b = 0;
#pragma unroll
      for (int by = 0; by < 4; ++by) {
        const int e = w * 4 + by;
        int q = (int)rintf(Wo[(wave * 64 + l4 * 16 + e) * 16 + l15] * 16384.0f);
        b |= (q & 255) << (8 * by);
      }
      wd[w] = b;
    }
    *reinterpret_cast<i32x4*>(wofs + wave * 1024 + lane * 16) =
        (i32x4){wd[0], wd[1], wd[2], wd[3]};
  }
  const float bh128 = 128.0f * bhn[wave * 16 + l15];
  const float bov = bo[l15];

  const int wrbase = (wave >> 2) * 1024 + ((wave & 3) * 16 + l4 * 4) * 16 + l15;

  // init h_0: lanes l4<2 hold the block's 8 rows; l4>=2 rows are zero
  float hcur[4];
  if (l4 < 2) {
#pragma unroll
    for (int j = 0; j < 4; ++j) {
      float h = carry0[(size_t)(r0 + l4 * 4 + j) * 256 + wave * 16 + l15];
      hcur[j] = h;
      float m = fmaf(h, 127.0f, FMAGIC);
      int hq = __builtin_bit_cast(int, m) - IMAGIC;
      ha[wrbase + j * 16] = (char)hq;
    }
  } else {
#pragma unroll
    for (int j = 0; j < 4; ++j) {
      hcur[j] = 0.0f;
      ha[wrbase + j * 16] = 0;
    }
  }
  __syncthreads();

  // gx: valid lanes (l4<2) read orig-lane = (2*half + l4)*16 + l15
  const f16* gp0 = gxL + (((size_t)blk * 8 + (wave >> 1)) * 6 +
                          (size_t)(wave & 1)) * 256 +
                   (size_t)(((2 * half + (l4 & 1)) * 16 + l15) * 4);

  auto head_tau = [&](int tau) {
    const int sbase = (tau & 7) * 4096;
    i32x4 aco = {};
#pragma unroll
    for (int kt = 0; kt < 4; ++kt) {
      i32x4 ah = *reinterpret_cast<const i32x4*>(ha + sbase + kt * 1024 + lane * 16);
      i32x4 wb = *reinterpret_cast<const i32x4*>(wofs + kt * 1024 + lane * 16);
      aco = __builtin_amdgcn_mfma_i32_16x16x64_i8(ah, wb, aco, 0, 0, 0);
    }
    if (l4 < 2) {
#pragma unroll
      for (int r = 0; r < 4; ++r) {
        float y = fmaf((float)aco[r], CHEAD, bov);
        if (l15 >= 8) y = __expf(fminf(fmaxf(y, -20.0f), 2.0f));
        out[((size_t)(tau - 1) * 256 + r0 + l4 * 4 + r) * 16 + l15] = y;
      }
    }
  };

  f16x4 gva[3], gvb[3];
#pragma unroll
  for (int g = 0; g < 3; ++g)
    gva[g] = *reinterpret_cast<const f16x4*>(gp0 + g * 512);

  auto step = [&](int cur, int nxt, f16x4 (&gv)[3], f16x4 (&gvn)[3],
                  const f16* gpn, int tt) {
    if ((tt & 7) == 0 && tt > 0) {
      if (wave < 8) head_tau(tt - 7 + wave);
      asm volatile("s_waitcnt lgkmcnt(0)\n\ts_barrier" ::: "memory");
    }
#pragma unroll
    for (int g = 0; g < 3; ++g)
      gvn[g] = *reinterpret_cast<const f16x4*>(gpn + g * 512);

    // kt-major: 3 independent acc chains interleaved (dep distance 3)
    i32x4 acc0 = {}, acc1 = {}, acc2 = {};
#pragma unroll
    for (int kt = 0; kt < 4; ++kt) {
      i32x4 a = *reinterpret_cast<const i32x4*>(ha + cur + kt * 1024 + lane * 16);
      acc0 = __builtin_amdgcn_mfma_i32_16x16x64_i8(a, whq[0][kt], acc0, 0, 0, 0);
      acc1 = __builtin_amdgcn_mfma_i32_16x16x64_i8(a, whq[1][kt], acc1, 0, 0, 0);
      acc2 = __builtin_amdgcn_mfma_i32_16x16x64_i8(a, whq[2][kt], acc2, 0, 0, 0);
    }

    if (l4 < 2) {
      // elementwise GRU (8 valid rows) + int8 A-frag write of h_{t+1}
#pragma unroll
      for (int j = 0; j < 4; ++j) {
        float pr = fmaf((float)acc0[j], CS, (float)gv[0][j]);
        float pz = fmaf((float)acc1[j], CS, (float)gv[1][j]);
        float pnh = fmaf((float)acc2[j], CS, bh128);
        float rg = sigm_s(pr);
        float zg = sigm_s(pz);
        float ng = tanh_s(fmaf(rg, pnh, (float)gv[2][j]));
        float h = ng + zg * (hcur[j] - ng);
        hcur[j] = h;
        float m = fmaf(h, 127.0f, FMAGIC);
        int hq = __builtin_bit_cast(int, m) - IMAGIC;
        ha[nxt + wrbase + j * 16] = (char)hq;
      }
    } else {
      // keep rows 8-15 of the next slot at zero
#pragma unroll
      for (int j = 0; j < 4; ++j) ha[nxt + wrbase + j * 16] = 0;
    }
    asm volatile("s_waitcnt lgkmcnt(0)\n\ts_barrier" ::: "memory");
  };

  for (int t = 0; t < 512; t += 2) {
    const f16* gp1 = gp0 + (size_t)(t + 1) * 196608;
    const f16* gp2 = gp0 + (size_t)(t + 2 <= 511 ? t + 2 : 511) * 196608;
    step((t & 7) * 4096, ((t + 1) & 7) * 4096, gva, gvb, gp1, t);
    step(((t + 1) & 7) * 4096, ((t + 2) & 7) * 4096, gvb, gva, gp2, t + 1);
  }

  if (wave < 8) head_tau(505 + wave);
}

extern "C" void kernel_launch(void* const* d_in, const int* in_sizes, int n_in,
                              void* d_out, int out_size, void* d_ws, size_t ws_size,
                              hipStream_t stream) {
  const float* x      = (const float*)d_in[0];
  const float* carry0 = (const float*)d_in[1];
  const float* Wi     = (const float*)d_in[2];
  const float* bi     = (const float*)d_in[3];
  const float* Wh     = (const float*)d_in[4];
  const float* bhn    = (const float*)d_in[5];
  const float* Wo     = (const float*)d_in[6];
  const float* bo     = (const float*)d_in[7];
  float* out = (float*)d_out;

  f16* gx  = (f16*)d_ws;                        // 512*256*768 f16 = 192 MiB
  f16* WiT = gx + (size_t)512 * 256 * 768;      // 768*256 f16 = 384 KiB
  f16* xh  = WiT + (size_t)768 * 256;           // 512*256*256 f16 = 64 MiB

  const size_t need = ((size_t)512 * 256 * 768 + (size_t)768 * 256 +
                       (size_t)512 * 256 * 256) * sizeof(f16);

  k_prep_wit<<<dim3(24, 8), dim3(32, 8), 0, stream>>>(Wi, WiT);
  if (ws_size >= need) {
    k_x16<<<dim3(2048), dim3(256), 0, stream>>>(x, xh);
    k_gemm_gx16<<<dim3(6, 1024), dim3(256), 0, stream>>>(xh, WiT, bi, gx);
  } else {
    k_gemm_gx<<<dim3(6, 1024), dim3(256), 0, stream>>>(x, WiT, bi, gx);
  }
  k_scan<<<dim3(32), dim3(1024), 0, stream>>>(carry0, Wh, bhn, gx, Wo, bo, out);
}

// Round 16
// 665.625 us; speedup vs baseline: 1.2276x; 1.2243x over previous
//
#include <hip/hip_runtime.h>
#include <hip/hip_fp16.h>

typedef _Float16 f16;
typedef __attribute__((ext_vector_type(8))) _Float16 f16x8;
typedef __attribute__((ext_vector_type(4))) _Float16 f16x4;
typedef __attribute__((ext_vector_type(2))) _Float16 f16x2;
typedef __attribute__((ext_vector_type(4))) float f32x4;
typedef __attribute__((ext_vector_type(4))) float float4v;
typedef __attribute__((ext_vector_type(4))) int i32x4;
typedef __attribute__((ext_vector_type(2))) int i32x2;

typedef __attribute__((address_space(3))) unsigned int lds_u32;
typedef const __attribute__((address_space(1))) unsigned int glb_u32;

// Shapes: x[512,256,256], carry0[256,256], Wi[256,768], bi[768],
//         Wh[256,768], bhn[256], Wo[256,16], bo[16] -> out[512,256,16] f32
//
// gx layout (scan-fragment order), f16, SCALED x128:
//   vecidx = ((t*16 + BLK)*8 + w8)*6 + (gate*2 + nt2); elem = vecidx*256+L*4+j
// Scan numerics (int8 MFMA, K=64): h int8 x127; Wh int8 x256; Wo int8 x16384;
// gx f16 as 128*(xWi+bi). preact*128 = gx + acc*CS; head y = acc*CHEAD.
//
// R16: 32 scan blocks x 8 rows; elementwise REDISTRIBUTED across all 64
// lanes via permlane32_swap (2 h-values/thread) — R15 showed masked lanes
// don't save issue time; moving work to them does.

#define CS 0.0039370079f        // 128/32512
#define CHEAD 4.805919e-7f      // 1/(127*16384)
#define FMAGIC 12582912.0f      // 1.5*2^23 (round-to-nearest-int trick)
#define IMAGIC 1262485504       // bit pattern of FMAGIC

static __device__ __forceinline__ float sigm_s(float x) {  // sigmoid(x/128)
  return __builtin_amdgcn_rcpf(1.0f + __expf(-0.0078125f * x));
}
static __device__ __forceinline__ float tanh_s(float x) {  // tanh(x/128)
  float e = __expf(0.015625f * x);
  return 1.0f - 2.0f * __builtin_amdgcn_rcpf(e + 1.0f);
}
// lanes 32-63 of result receive v's lanes 0-31 (vdst-hi <-> vsrc-lo swap;
// robust under operand aliasing or copying)
static __device__ __forceinline__ int hi_from_lo(int v) {
#if __has_builtin(__builtin_amdgcn_permlane32_swap)
  i32x2 r = __builtin_amdgcn_permlane32_swap(v, v, false, false);
  return r.x;
#else
  return __shfl_xor(v, 32, 64);
#endif
}

// ---------------- K0: tiled transpose Wi[256,768] -> WiT[768][256] f16 ------
__global__ void k_prep_wit(const float* __restrict__ Wi, f16* __restrict__ WiT) {
  __shared__ float tile[32][33];
  const int n0 = blockIdx.x * 32;
  const int k0 = blockIdx.y * 32;
  const int tx = threadIdx.x, ty = threadIdx.y;  // (32, 8)
#pragma unroll
  for (int i = 0; i < 4; ++i)
    tile[ty + i * 8][tx] = Wi[(size_t)(k0 + ty + i * 8) * 768 + n0 + tx];
  __syncthreads();
#pragma unroll
  for (int i = 0; i < 4; ++i)
    WiT[(size_t)(n0 + ty + i * 8) * 256 + k0 + tx] = (f16)tile[tx][ty + i * 8];
}

// ---------------- K0b: x f32 -> f16 (memory-bound pass) ---------------------
__global__ __launch_bounds__(256) void k_x16(const float* __restrict__ x,
                                             f16* __restrict__ x16) {
  size_t i = ((size_t)blockIdx.x * 256 + threadIdx.x) * 4;
  const size_t stride = (size_t)gridDim.x * 1024;
  for (; i < (size_t)512 * 256 * 256; i += stride) {
    float4v v = *reinterpret_cast<const float4v*>(x + i);
    f16x4 h;
    h[0] = (f16)v[0]; h[1] = (f16)v[1]; h[2] = (f16)v[2]; h[3] = (f16)v[3];
    *reinterpret_cast<f16x4*>(x16 + i) = h;
  }
}

// ---------------- K1 fast: gx = 128*(x16 @ Wi + bi), global_load_lds --------
__global__ __launch_bounds__(256, 4) void k_gemm_gx16(
    const f16* __restrict__ x16, const f16* __restrict__ WiT,
    const float* __restrict__ bi, f16* __restrict__ gx) {
  __shared__ f16 As[128 * 64];
  __shared__ f16 Bs[128 * 64];
  const int tid = threadIdx.x;
  const int lane = tid & 63;
  const int wave = tid >> 6;
  const int wm = wave >> 1, wn = wave & 1;
  const int m0 = blockIdx.y * 128;
  const int n0 = blockIdx.x * 128;

  const f16* aSrc[4];
  const f16* bSrc[4];
#pragma unroll
  for (int i = 0; i < 4; ++i) {
    const int s = (wave * 4 + i) * 64 + lane;
    const int row = s >> 3, cx = s & 7;
    const int g = cx ^ (row & 7);
    aSrc[i] = x16 + (size_t)(m0 + row) * 256 + g * 8;
    bSrc[i] = WiT + (size_t)(n0 + row) * 256 + g * 8;
  }

  f32x4 acc[4][4] = {};

  for (int ks = 0; ks < 4; ++ks) {
#pragma unroll
    for (int i = 0; i < 4; ++i) {
      __builtin_amdgcn_global_load_lds(
          (glb_u32*)(aSrc[i] + ks * 64),
          (lds_u32*)(reinterpret_cast<char*>(As) + (wave * 4 + i) * 1024), 16, 0, 0);
      __builtin_amdgcn_global_load_lds(
          (glb_u32*)(bSrc[i] + ks * 64),
          (lds_u32*)(reinterpret_cast<char*>(Bs) + (wave * 4 + i) * 1024), 16, 0, 0);
    }
    asm volatile("s_waitcnt vmcnt(0)" ::: "memory");
    __syncthreads();
#pragma unroll
    for (int kt = 0; kt < 2; ++kt) {
      const int kb = kt * 64 + ((lane >> 4) << 4);
      f16x8 a[4], b[4];
#pragma unroll
      for (int mt = 0; mt < 4; ++mt) {
        int r = wm * 64 + mt * 16 + (lane & 15);
        a[mt] = *reinterpret_cast<const f16x8*>(
            reinterpret_cast<const char*>(As) + r * 128 + (kb ^ ((r & 7) << 4)));
      }
#pragma unroll
      for (int nt = 0; nt < 4; ++nt) {
        int r = wn * 64 + nt * 16 + (lane & 15);
        b[nt] = *reinterpret_cast<const f16x8*>(
            reinterpret_cast<const char*>(Bs) + r * 128 + (kb ^ ((r & 7) << 4)));
      }
#pragma unroll
      for (int mt = 0; mt < 4; ++mt)
#pragma unroll
        for (int nt = 0; nt < 4; ++nt)
          acc[mt][nt] = __builtin_amdgcn_mfma_f32_16x16x32_f16(
              a[mt], b[nt], acc[mt][nt], 0, 0, 0);
    }
    __syncthreads();
  }
  const int t_  = blockIdx.y >> 1;
  const int bhf = blockIdx.y & 1;
  const int gg  = blockIdx.x >> 1;
  const int xh  = blockIdx.x & 1;
  float biv[4];
#pragma unroll
  for (int nt = 0; nt < 4; ++nt) biv[nt] = bi[n0 + wn * 64 + nt * 16 + (lane & 15)];
#pragma unroll
  for (int mt = 0; mt < 4; ++mt) {
    const int blk = bhf * 8 + wm * 4 + mt;
#pragma unroll
    for (int nt = 0; nt < 4; ++nt) {
      const int w = xh * 4 + wn * 2 + (nt >> 1);
      const int vecidx = ((t_ * 16 + blk) * 8 + w) * 6 + gg * 2 + (nt & 1);
      f16x4 hv;
#pragma unroll
      for (int r = 0; r < 4; ++r)
        hv[r] = (f16)((acc[mt][nt][r] + biv[nt]) * 128.0f);
      *reinterpret_cast<f16x4*>(gx + (size_t)vecidx * 256 + lane * 4) = hv;
    }
  }
}

// ---------------- K1 fallback: gx from f32 x --------------------------------
__global__ __launch_bounds__(256, 4) void k_gemm_gx(
    const float* __restrict__ x, const f16* __restrict__ WiT,
    const float* __restrict__ bi, f16* __restrict__ gx) {
  __shared__ f16 As[128 * 64];
  __shared__ f16 Bs[128 * 64];
  const int tid = threadIdx.x;
  const int lane = tid & 63;
  const int wave = tid >> 6;
  const int wm = wave >> 1, wn = wave & 1;
  const int m0 = blockIdx.y * 128;
  const int n0 = blockIdx.x * 128;

  f32x4 acc[4][4] = {};

  for (int ks = 0; ks < 4; ++ks) {
    const int k0 = ks * 64;
#pragma unroll
    for (int i = 0; i < 8; ++i) {
      int c = i * 256 + tid;
      int row = c >> 4, cx = c & 15;
      float4v v = *reinterpret_cast<const float4v*>(
          x + (size_t)(m0 + row) * 256 + k0 + cx * 4);
      f16x4 hv;
      hv[0] = (f16)v[0]; hv[1] = (f16)v[1]; hv[2] = (f16)v[2]; hv[3] = (f16)v[3];
      int boff = row * 128 + ((cx * 8) ^ ((row & 7) << 4));
      *reinterpret_cast<f16x4*>(reinterpret_cast<char*>(As) + boff) = hv;
    }
#pragma unroll
    for (int i = 0; i < 4; ++i) {
      int c = i * 256 + tid;
      int n = c >> 3, cx = c & 7;
      f16x8 v = *reinterpret_cast<const f16x8*>(
          WiT + (size_t)(n0 + n) * 256 + k0 + cx * 8);
      int boff = n * 128 + ((cx * 16) ^ ((n & 7) << 4));
      *reinterpret_cast<f16x8*>(reinterpret_cast<char*>(Bs) + boff) = v;
    }
    __syncthreads();
#pragma unroll
    for (int kt = 0; kt < 2; ++kt) {
      const int kb = kt * 64 + ((lane >> 4) << 4);
      f16x8 a[4], b[4];
#pragma unroll
      for (int mt = 0; mt < 4; ++mt) {
        int r = wm * 64 + mt * 16 + (lane & 15);
        a[mt] = *reinterpret_cast<const f16x8*>(
            reinterpret_cast<const char*>(As) + r * 128 + (kb ^ ((r & 7) << 4)));
      }
#pragma unroll
      for (int nt = 0; nt < 4; ++nt) {
        int r = wn * 64 + nt * 16 + (lane & 15);
        b[nt] = *reinterpret_cast<const f16x8*>(
            reinterpret_cast<const char*>(Bs) + r * 128 + (kb ^ ((r & 7) << 4)));
      }
#pragma unroll
      for (int mt = 0; mt < 4; ++mt)
#pragma unroll
        for (int nt = 0; nt < 4; ++nt)
          acc[mt][nt] = __builtin_amdgcn_mfma_f32_16x16x32_f16(
              a[mt], b[nt], acc[mt][nt], 0, 0, 0);
    }
    __syncthreads();
  }
  const int t_  = blockIdx.y >> 1;
  const int bhf = blockIdx.y & 1;
  const int gg  = blockIdx.x >> 1;
  const int xh  = blockIdx.x & 1;
  float biv[4];
#pragma unroll
  for (int nt = 0; nt < 4; ++nt) biv[nt] = bi[n0 + wn * 64 + nt * 16 + (lane & 15)];
#pragma unroll
  for (int mt = 0; mt < 4; ++mt) {
    const int blk = bhf * 8 + wm * 4 + mt;
#pragma unroll
    for (int nt = 0; nt < 4; ++nt) {
      const int w = xh * 4 + wn * 2 + (nt >> 1);
      const int vecidx = ((t_ * 16 + blk) * 8 + w) * 6 + gg * 2 + (nt & 1);
      f16x4 hv;
#pragma unroll
      for (int r = 0; r < 4; ++r)
        hv[r] = (f16)((acc[mt][nt][r] + biv[nt]) * 128.0f);
      *reinterpret_cast<f16x4*>(gx + (size_t)vecidx * 256 + lane * 4) = hv;
    }
  }
}

// ---------------- K2: int8 GRU scan, 32 blocks x 8 rows, redistributed ------
// Block (blk = bid>>1, half = bid&1) owns batch rows blk*16 + half*8 .. +7.
// MFMA tiles M=16 with rows 8-15 statically zero (all 8 ring slots zeroed at
// init, never rewritten). After MFMA, permlane32_swap hands j=2,3 acc values
// to lanes 32-63: every thread runs elementwise for 2 h-values.
__global__ __launch_bounds__(1024) void k_scan(
    const float* __restrict__ carry0, const float* __restrict__ Wh,
    const float* __restrict__ bhn, const f16* __restrict__ gxL,
    const float* __restrict__ Wo, const float* __restrict__ bo,
    float* __restrict__ out) {
  __shared__ __align__(16) char ha[8 * 4096];   // 32 KB: h ring, 8 slots
  __shared__ __align__(16) char wofs[4 * 1024]; // 4 KB: Wo int8 B-frags
  const int tid = threadIdx.x;
  const int lane = tid & 63;
  const int wave = tid >> 6;  // 0..15
  const int l15 = lane & 15, l4 = lane >> 4;
  const int blk = blockIdx.x >> 1;
  const int half = blockIdx.x & 1;
  const int r0 = blk * 16 + half * 8;  // 8 batch rows

  i32x4 whq[3][4];
#pragma unroll
  for (int g = 0; g < 3; ++g) {
    const int col = g * 256 + wave * 16 + l15;
#pragma unroll
    for (int kt = 0; kt < 4; ++kt) {
      int wd[4];
#pragma unroll
      for (int w = 0; w < 4; ++w) {
        int b = 0;
#pragma unroll
        for (int by = 0; by < 4; ++by) {
          const int e = w * 4 + by;
          int q = (int)rintf(Wh[(size_t)(kt * 64 + l4 * 16 + e) * 768 + col] *
                             256.0f);
          b |= (q & 255) << (8 * by);
        }
        wd[w] = b;
      }
      whq[g][kt] = (i32x4){wd[0], wd[1], wd[2], wd[3]};
    }
  }
  if (wave < 4) {
    int wd[4];
#pragma unroll
    for (int w = 0; w < 4; ++w) {
      int b = 0;
#pragma unroll
      for (int by = 0; by < 4; ++by) {
        const int e = w * 4 + by;
        int q = (int)rintf(Wo[(wave * 64 + l4 * 16 + e) * 16 + l15] * 16384.0f);
        b |= (q & 255) << (8 * by);
      }
      wd[w] = b;
    }
    *reinterpret_cast<i32x4*>(wofs + wave * 1024 + lane * 16) =
        (i32x4){wd[0], wd[1], wd[2], wd[3]};
  }
  const float bh128 = 128.0f * bhn[wave * 16 + l15];
  const float bov = bo[l15];

  // zero ALL ring slots (rows 8-15 rely on this; rows 0-7 overwritten below)
#pragma unroll
  for (int i = 0; i < 2; ++i)
    *reinterpret_cast<i32x4*>(ha + tid * 32 + i * 16) = (i32x4){0, 0, 0, 0};
  __syncthreads();

  // redistribution geometry: this thread owns rows rA, rA+1 (within 0..7)
  const int jA = (lane >= 32) ? 2 : 0;
  const int rA = (l4 & 1) * 4 + jA;
  const int wrb = (wave >> 2) * 1024 + ((wave & 3) * 16 + rA) * 16 + l15;

  float hcur[2];
#pragma unroll
  for (int v = 0; v < 2; ++v) {
    float h = carry0[(size_t)(r0 + rA + v) * 256 + wave * 16 + l15];
    hcur[v] = h;
    float m = fmaf(h, 127.0f, FMAGIC);
    int hq = __builtin_bit_cast(int, m) - IMAGIC;
    ha[wrb + v * 16] = (char)hq;
  }
  __syncthreads();

  // gx address: original fragment lane Lg with element pair (jA, jA+1)
  const int Lg = (half * 2 + (l4 & 1)) * 16 + l15;
  const f16* gp0 = gxL + (((size_t)blk * 8 + (wave >> 1)) * 6 +
                          (size_t)(wave & 1)) * 256 + (size_t)Lg * 4 + jA;

  auto head_tau = [&](int tau) {
    const int sbase = (tau & 7) * 4096;
    i32x4 aco = {};
#pragma unroll
    for (int kt = 0; kt < 4; ++kt) {
      i32x4 ah = *reinterpret_cast<const i32x4*>(ha + sbase + kt * 1024 + lane * 16);
      i32x4 wb = *reinterpret_cast<const i32x4*>(wofs + kt * 1024 + lane * 16);
      aco = __builtin_amdgcn_mfma_i32_16x16x64_i8(ah, wb, aco, 0, 0, 0);
    }
    if (l4 < 2) {
#pragma unroll
      for (int r = 0; r < 4; ++r) {
        float y = fmaf((float)aco[r], CHEAD, bov);
        if (l15 >= 8) y = __expf(fminf(fmaxf(y, -20.0f), 2.0f));
        out[((size_t)(tau - 1) * 256 + r0 + l4 * 4 + r) * 16 + l15] = y;
      }
    }
  };

  f16x2 gva[3], gvb[3];
#pragma unroll
  for (int g = 0; g < 3; ++g)
    gva[g] = *reinterpret_cast<const f16x2*>(gp0 + g * 512);

  auto step = [&](int cur, int nxt, f16x2 (&gv)[3], f16x2 (&gvn)[3],
                  const f16* gpn, int tt) {
    if ((tt & 7) == 0 && tt > 0) {
      if (wave < 8) head_tau(tt - 7 + wave);
      asm volatile("s_waitcnt lgkmcnt(0)\n\ts_barrier" ::: "memory");
    }
#pragma unroll
    for (int g = 0; g < 3; ++g)
      gvn[g] = *reinterpret_cast<const f16x2*>(gpn + g * 512);

    // kt-major: 3 independent acc chains interleaved (dep distance 3)
    i32x4 acc0 = {}, acc1 = {}, acc2 = {};
#pragma unroll
    for (int kt = 0; kt < 4; ++kt) {
      i32x4 a = *reinterpret_cast<const i32x4*>(ha + cur + kt * 1024 + lane * 16);
      acc0 = __builtin_amdgcn_mfma_i32_16x16x64_i8(a, whq[0][kt], acc0, 0, 0, 0);
      acc1 = __builtin_amdgcn_mfma_i32_16x16x64_i8(a, whq[1][kt], acc1, 0, 0, 0);
      acc2 = __builtin_amdgcn_mfma_i32_16x16x64_i8(a, whq[2][kt], acc2, 0, 0, 0);
    }

    // redistribute j=2,3 to lanes 32-63 (each thread: 2 h-values)
    const int s02 = hi_from_lo(acc0[2]), s03 = hi_from_lo(acc0[3]);
    const int s12 = hi_from_lo(acc1[2]), s13 = hi_from_lo(acc1[3]);
    const int s22 = hi_from_lo(acc2[2]), s23 = hi_from_lo(acc2[3]);
    const bool up = lane >= 32;
    const int a0[2] = {up ? s02 : acc0[0], up ? s03 : acc0[1]};
    const int a1[2] = {up ? s12 : acc1[0], up ? s13 : acc1[1]};
    const int a2[2] = {up ? s22 : acc2[0], up ? s23 : acc2[1]};

#pragma unroll
    for (int v = 0; v < 2; ++v) {
      float pr = fmaf((float)a0[v], CS, (float)gv[0][v]);
      float pz = fmaf((float)a1[v], CS, (float)gv[1][v]);
      float pnh = fmaf((float)a2[v], CS, bh128);
      float rg = sigm_s(pr);
      float zg = sigm_s(pz);
      float ng = tanh_s(fmaf(rg, pnh, (float)gv[2][v]));
      float h = ng + zg * (hcur[v] - ng);
      hcur[v] = h;
      float m = fmaf(h, 127.0f, FMAGIC);
      int hq = __builtin_bit_cast(int, m) - IMAGIC;
      ha[nxt + wrb + v * 16] = (char)hq;
    }
    asm volatile("s_waitcnt lgkmcnt(0)\n\ts_barrier" ::: "memory");
  };

  for (int t = 0; t < 512; t += 2) {
    const f16* gp1 = gp0 + (size_t)(t + 1) * 196608;
    const f16* gp2 = gp0 + (size_t)(t + 2 <= 511 ? t + 2 : 511) * 196608;
    step((t & 7) * 4096, ((t + 1) & 7) * 4096, gva, gvb, gp1, t);
    step(((t + 1) & 7) * 4096, ((t + 2) & 7) * 4096, gvb, gva, gp2, t + 1);
  }

  if (wave < 8) head_tau(505 + wave);
}

extern "C" void kernel_launch(void* const* d_in, const int* in_sizes, int n_in,
                              void* d_out, int out_size, void* d_ws, size_t ws_size,
                              hipStream_t stream) {
  const float* x      = (const float*)d_in[0];
  const float* carry0 = (const float*)d_in[1];
  const float* Wi     = (const float*)d_in[2];
  const float* bi     = (const float*)d_in[3];
  const float* Wh     = (const float*)d_in[4];
  const float* bhn    = (const float*)d_in[5];
  const float* Wo     = (const float*)d_in[6];
  const float* bo     = (const float*)d_in[7];
  float* out = (float*)d_out;

  f16* gx  = (f16*)d_ws;                        // 512*256*768 f16 = 192 MiB
  f16* WiT = gx + (size_t)512 * 256 * 768;      // 768*256 f16 = 384 KiB
  f16* xh  = WiT + (size_t)768 * 256;           // 512*256*256 f16 = 64 MiB

  const size_t need = ((size_t)512 * 256 * 768 + (size_t)768 * 256 +
                       (size_t)512 * 256 * 256) * sizeof(f16);

  k_prep_wit<<<dim3(24, 8), dim3(32, 8), 0, stream>>>(Wi, WiT);
  if (ws_size >= need) {
    k_x16<<<dim3(2048), dim3(256), 0, stream>>>(x, xh);
    k_gemm_gx16<<<dim3(6, 1024), dim3(256), 0, stream>>>(xh, WiT, bi, gx);
  } else {
    k_gemm_gx<<<dim3(6, 1024), dim3(256), 0, stream>>>(x, WiT, bi, gx);
  }
  k_scan<<<dim3(32), dim3(1024), 0, stream>>>(carry0, Wh, bhn, gx, Wo, bo, out);
}

// Round 17
// 521.801 us; speedup vs baseline: 1.5660x; 1.2756x over previous
//
#include <hip/hip_runtime.h>
#include <hip/hip_fp16.h>

typedef _Float16 f16;
typedef __attribute__((ext_vector_type(8))) _Float16 f16x8;
typedef __attribute__((ext_vector_type(4))) _Float16 f16x4;
typedef __attribute__((ext_vector_type(4))) float f32x4;
typedef __attribute__((ext_vector_type(4))) float float4v;
typedef __attribute__((ext_vector_type(4))) int i32x4;

typedef __attribute__((address_space(3))) unsigned int lds_u32;
typedef const __attribute__((address_space(1))) unsigned int glb_u32;

// Shapes: x[512,256,256], carry0[256,256], Wi[256,768], bi[768],
//         Wh[256,768], bhn[256], Wo[256,16], bo[16] -> out[512,256,16] f32
//
// gx layout (scan-fragment order), f16, SCALED x128:
//   vecidx = ((t*16 + BLK)*8 + w8)*6 + (gate*2 + nt2); elem = vecidx*256+L*4+j
// Scan numerics (int8 MFMA, K=64): h int8 x127; Wh int8 x256; Wo int8 x16384;
// gx f16 as 128*(xWi+bi). preact*128 = gx + acc*CS; head y = acc*CHEAD.
//
// R17: 64 scan blocks x 4 rows. Valid batch rows placed at TILE rows
// {0,4,8,12} so j=0 of every 16-lane group holds a valid row: exactly one
// h-value per thread, NO cross-lane swaps (removes R16's permlane overhead).
// Rows !=0 (mod 4) statically zero (ring zeroed once at init).

#define CS 0.0039370079f        // 128/32512
#define CHEAD 4.805919e-7f      // 1/(127*16384)
#define FMAGIC 12582912.0f      // 1.5*2^23 (round-to-nearest-int trick)
#define IMAGIC 1262485504       // bit pattern of FMAGIC

static __device__ __forceinline__ float sigm_s(float x) {  // sigmoid(x/128)
  return __builtin_amdgcn_rcpf(1.0f + __expf(-0.0078125f * x));
}
static __device__ __forceinline__ float tanh_s(float x) {  // tanh(x/128)
  float e = __expf(0.015625f * x);
  return 1.0f - 2.0f * __builtin_amdgcn_rcpf(e + 1.0f);
}

// ---------------- K0: tiled transpose Wi[256,768] -> WiT[768][256] f16 ------
__global__ void k_prep_wit(const float* __restrict__ Wi, f16* __restrict__ WiT) {
  __shared__ float tile[32][33];
  const int n0 = blockIdx.x * 32;
  const int k0 = blockIdx.y * 32;
  const int tx = threadIdx.x, ty = threadIdx.y;  // (32, 8)
#pragma unroll
  for (int i = 0; i < 4; ++i)
    tile[ty + i * 8][tx] = Wi[(size_t)(k0 + ty + i * 8) * 768 + n0 + tx];
  __syncthreads();
#pragma unroll
  for (int i = 0; i < 4; ++i)
    WiT[(size_t)(n0 + ty + i * 8) * 256 + k0 + tx] = (f16)tile[tx][ty + i * 8];
}

// ---------------- K0b: x f32 -> f16 (memory-bound pass) ---------------------
__global__ __launch_bounds__(256) void k_x16(const float* __restrict__ x,
                                             f16* __restrict__ x16) {
  size_t i = ((size_t)blockIdx.x * 256 + threadIdx.x) * 4;
  const size_t stride = (size_t)gridDim.x * 1024;
  for (; i < (size_t)512 * 256 * 256; i += stride) {
    float4v v = *reinterpret_cast<const float4v*>(x + i);
    f16x4 h;
    h[0] = (f16)v[0]; h[1] = (f16)v[1]; h[2] = (f16)v[2]; h[3] = (f16)v[3];
    *reinterpret_cast<f16x4*>(x16 + i) = h;
  }
}

// ---------------- K1 fast: gx = 128*(x16 @ Wi + bi), global_load_lds --------
__global__ __launch_bounds__(256, 4) void k_gemm_gx16(
    const f16* __restrict__ x16, const f16* __restrict__ WiT,
    const float* __restrict__ bi, f16* __restrict__ gx) {
  __shared__ f16 As[128 * 64];
  __shared__ f16 Bs[128 * 64];
  const int tid = threadIdx.x;
  const int lane = tid & 63;
  const int wave = tid >> 6;
  const int wm = wave >> 1, wn = wave & 1;
  const int m0 = blockIdx.y * 128;
  const int n0 = blockIdx.x * 128;

  const f16* aSrc[4];
  const f16* bSrc[4];
#pragma unroll
  for (int i = 0; i < 4; ++i) {
    const int s = (wave * 4 + i) * 64 + lane;
    const int row = s >> 3, cx = s & 7;
    const int g = cx ^ (row & 7);
    aSrc[i] = x16 + (size_t)(m0 + row) * 256 + g * 8;
    bSrc[i] = WiT + (size_t)(n0 + row) * 256 + g * 8;
  }

  f32x4 acc[4][4] = {};

  for (int ks = 0; ks < 4; ++ks) {
#pragma unroll
    for (int i = 0; i < 4; ++i) {
      __builtin_amdgcn_global_load_lds(
          (glb_u32*)(aSrc[i] + ks * 64),
          (lds_u32*)(reinterpret_cast<char*>(As) + (wave * 4 + i) * 1024), 16, 0, 0);
      __builtin_amdgcn_global_load_lds(
          (glb_u32*)(bSrc[i] + ks * 64),
          (lds_u32*)(reinterpret_cast<char*>(Bs) + (wave * 4 + i) * 1024), 16, 0, 0);
    }
    asm volatile("s_waitcnt vmcnt(0)" ::: "memory");
    __syncthreads();
#pragma unroll
    for (int kt = 0; kt < 2; ++kt) {
      const int kb = kt * 64 + ((lane >> 4) << 4);
      f16x8 a[4], b[4];
#pragma unroll
      for (int mt = 0; mt < 4; ++mt) {
        int r = wm * 64 + mt * 16 + (lane & 15);
        a[mt] = *reinterpret_cast<const f16x8*>(
            reinterpret_cast<const char*>(As) + r * 128 + (kb ^ ((r & 7) << 4)));
      }
#pragma unroll
      for (int nt = 0; nt < 4; ++nt) {
        int r = wn * 64 + nt * 16 + (lane & 15);
        b[nt] = *reinterpret_cast<const f16x8*>(
            reinterpret_cast<const char*>(Bs) + r * 128 + (kb ^ ((r & 7) << 4)));
      }
#pragma unroll
      for (int mt = 0; mt < 4; ++mt)
#pragma unroll
        for (int nt = 0; nt < 4; ++nt)
          acc[mt][nt] = __builtin_amdgcn_mfma_f32_16x16x32_f16(
              a[mt], b[nt], acc[mt][nt], 0, 0, 0);
    }
    __syncthreads();
  }
  const int t_  = blockIdx.y >> 1;
  const int bhf = blockIdx.y & 1;
  const int gg  = blockIdx.x >> 1;
  const int xh  = blockIdx.x & 1;
  float biv[4];
#pragma unroll
  for (int nt = 0; nt < 4; ++nt) biv[nt] = bi[n0 + wn * 64 + nt * 16 + (lane & 15)];
#pragma unroll
  for (int mt = 0; mt < 4; ++mt) {
    const int blk = bhf * 8 + wm * 4 + mt;
#pragma unroll
    for (int nt = 0; nt < 4; ++nt) {
      const int w = xh * 4 + wn * 2 + (nt >> 1);
      const int vecidx = ((t_ * 16 + blk) * 8 + w) * 6 + gg * 2 + (nt & 1);
      f16x4 hv;
#pragma unroll
      for (int r = 0; r < 4; ++r)
        hv[r] = (f16)((acc[mt][nt][r] + biv[nt]) * 128.0f);
      *reinterpret_cast<f16x4*>(gx + (size_t)vecidx * 256 + lane * 4) = hv;
    }
  }
}

// ---------------- K1 fallback: gx from f32 x --------------------------------
__global__ __launch_bounds__(256, 4) void k_gemm_gx(
    const float* __restrict__ x, const f16* __restrict__ WiT,
    const float* __restrict__ bi, f16* __restrict__ gx) {
  __shared__ f16 As[128 * 64];
  __shared__ f16 Bs[128 * 64];
  const int tid = threadIdx.x;
  const int lane = tid & 63;
  const int wave = tid >> 6;
  const int wm = wave >> 1, wn = wave & 1;
  const int m0 = blockIdx.y * 128;
  const int n0 = blockIdx.x * 128;

  f32x4 acc[4][4] = {};

  for (int ks = 0; ks < 4; ++ks) {
    const int k0 = ks * 64;
#pragma unroll
    for (int i = 0; i < 8; ++i) {
      int c = i * 256 + tid;
      int row = c >> 4, cx = c & 15;
      float4v v = *reinterpret_cast<const float4v*>(
          x + (size_t)(m0 + row) * 256 + k0 + cx * 4);
      f16x4 hv;
      hv[0] = (f16)v[0]; hv[1] = (f16)v[1]; hv[2] = (f16)v[2]; hv[3] = (f16)v[3];
      int boff = row * 128 + ((cx * 8) ^ ((row & 7) << 4));
      *reinterpret_cast<f16x4*>(reinterpret_cast<char*>(As) + boff) = hv;
    }
#pragma unroll
    for (int i = 0; i < 4; ++i) {
      int c = i * 256 + tid;
      int n = c >> 3, cx = c & 7;
      f16x8 v = *reinterpret_cast<const f16x8*>(
          WiT + (size_t)(n0 + n) * 256 + k0 + cx * 8);
      int boff = n * 128 + ((cx * 16) ^ ((n & 7) << 4));
      *reinterpret_cast<f16x8*>(reinterpret_cast<char*>(Bs) + boff) = v;
    }
    __syncthreads();
#pragma unroll
    for (int kt = 0; kt < 2; ++kt) {
      const int kb = kt * 64 + ((lane >> 4) << 4);
      f16x8 a[4], b[4];
#pragma unroll
      for (int mt = 0; mt < 4; ++mt) {
        int r = wm * 64 + mt * 16 + (lane & 15);
        a[mt] = *reinterpret_cast<const f16x8*>(
            reinterpret_cast<const char*>(As) + r * 128 + (kb ^ ((r & 7) << 4)));
      }
#pragma unroll
      for (int nt = 0; nt < 4; ++nt) {
        int r = wn * 64 + nt * 16 + (lane & 15);
        b[nt] = *reinterpret_cast<const f16x8*>(
            reinterpret_cast<const char*>(Bs) + r * 128 + (kb ^ ((r & 7) << 4)));
      }
#pragma unroll
      for (int mt = 0; mt < 4; ++mt)
#pragma unroll
        for (int nt = 0; nt < 4; ++nt)
          acc[mt][nt] = __builtin_amdgcn_mfma_f32_16x16x32_f16(
              a[mt], b[nt], acc[mt][nt], 0, 0, 0);
    }
    __syncthreads();
  }
  const int t_  = blockIdx.y >> 1;
  const int bhf = blockIdx.y & 1;
  const int gg  = blockIdx.x >> 1;
  const int xh  = blockIdx.x & 1;
  float biv[4];
#pragma unroll
  for (int nt = 0; nt < 4; ++nt) biv[nt] = bi[n0 + wn * 64 + nt * 16 + (lane & 15)];
#pragma unroll
  for (int mt = 0; mt < 4; ++mt) {
    const int blk = bhf * 8 + wm * 4 + mt;
#pragma unroll
    for (int nt = 0; nt < 4; ++nt) {
      const int w = xh * 4 + wn * 2 + (nt >> 1);
      const int vecidx = ((t_ * 16 + blk) * 8 + w) * 6 + gg * 2 + (nt & 1);
      f16x4 hv;
#pragma unroll
      for (int r = 0; r < 4; ++r)
        hv[r] = (f16)((acc[mt][nt][r] + biv[nt]) * 128.0f);
      *reinterpret_cast<f16x4*>(gx + (size_t)vecidx * 256 + lane * 4) = hv;
    }
  }
}

// ---------------- K2: int8 GRU scan, 64 blocks x 4 rows ---------------------
// Block (blk = bid>>2, q = bid&3) owns batch rows blk*16 + q*4 .. +3, placed
// at TILE rows {0,4,8,12} (row 4p for batch offset p). j=0 of each 16-lane
// group is a valid row -> 1 h-value/thread, no shuffles. Rows %4!=0 of all
// ring slots zeroed once. kt-major MFMA interleave (dep distance 3).
__global__ __launch_bounds__(1024) void k_scan(
    const float* __restrict__ carry0, const float* __restrict__ Wh,
    const float* __restrict__ bhn, const f16* __restrict__ gxL,
    const float* __restrict__ Wo, const float* __restrict__ bo,
    float* __restrict__ out) {
  __shared__ __align__(16) char ha[8 * 4096];   // 32 KB: h ring, 8 slots
  __shared__ __align__(16) char wofs[4 * 1024]; // 4 KB: Wo int8 B-frags
  const int tid = threadIdx.x;
  const int lane = tid & 63;
  const int wave = tid >> 6;  // 0..15
  const int l15 = lane & 15, l4 = lane >> 4;
  const int blk = blockIdx.x >> 2;
  const int q = blockIdx.x & 3;
  const int r0 = blk * 16 + q * 4;  // 4 batch rows; this thread owns r0+l4

  i32x4 whq[3][4];
#pragma unroll
  for (int g = 0; g < 3; ++g) {
    const int col = g * 256 + wave * 16 + l15;
#pragma unroll
    for (int kt = 0; kt < 4; ++kt) {
      int wd[4];
#pragma unroll
      for (int w = 0; w < 4; ++w) {
        int b = 0;
#pragma unroll
        for (int by = 0; by < 4; ++by) {
          const int e = w * 4 + by;
          int qq = (int)rintf(Wh[(size_t)(kt * 64 + l4 * 16 + e) * 768 + col] *
                              256.0f);
          b |= (qq & 255) << (8 * by);
        }
        wd[w] = b;
      }
      whq[g][kt] = (i32x4){wd[0], wd[1], wd[2], wd[3]};
    }
  }
  if (wave < 4) {
    int wd[4];
#pragma unroll
    for (int w = 0; w < 4; ++w) {
      int b = 0;
#pragma unroll
      for (int by = 0; by < 4; ++by) {
        const int e = w * 4 + by;
        int qq = (int)rintf(Wo[(wave * 64 + l4 * 16 + e) * 16 + l15] * 16384.0f);
        b |= (qq & 255) << (8 * by);
      }
      wd[w] = b;
    }
    *reinterpret_cast<i32x4*>(wofs + wave * 1024 + lane * 16) =
        (i32x4){wd[0], wd[1], wd[2], wd[3]};
  }
  const float bh128 = 128.0f * bhn[wave * 16 + l15];
  const float bov = bo[l15];

  // zero ALL ring slots (rows %4 != 0 rely on this permanently)
#pragma unroll
  for (int i = 0; i < 2; ++i)
    *reinterpret_cast<i32x4*>(ha + tid * 32 + i * 16) = (i32x4){0, 0, 0, 0};
  __syncthreads();

  // h write address: batch offset p = l4 -> tile row 4*l4
  // frame = wave>>2, granule = (wave&3)*16 + 4*l4, byte = l15
  const int wrb = (wave >> 2) * 1024 + ((wave & 3) * 16 + l4 * 4) * 16 + l15;

  float hcur;
  {
    float h = carry0[(size_t)(r0 + l4) * 256 + wave * 16 + l15];
    hcur = h;
    float m = fmaf(h, 127.0f, FMAGIC);
    int hq = __builtin_bit_cast(int, m) - IMAGIC;
    ha[wrb] = (char)hq;
  }
  __syncthreads();

  // gx element for (batch row-in-16blk = q*4 + l4, col = wave*16+l15):
  // fragment lane Lg = q*16 + l15, element j = l4
  const f16* gp0 = gxL + (((size_t)blk * 8 + (wave >> 1)) * 6 +
                          (size_t)(wave & 1)) * 256 +
                   (size_t)(q * 16 + l15) * 4 + l4;

  auto head_tau = [&](int tau) {
    const int sbase = (tau & 7) * 4096;
    i32x4 aco = {};
#pragma unroll
    for (int kt = 0; kt < 4; ++kt) {
      i32x4 ah = *reinterpret_cast<const i32x4*>(ha + sbase + kt * 1024 + lane * 16);
      i32x4 wb = *reinterpret_cast<const i32x4*>(wofs + kt * 1024 + lane * 16);
      aco = __builtin_amdgcn_mfma_i32_16x16x64_i8(ah, wb, aco, 0, 0, 0);
    }
    // valid C rows are 4*l4 (r=0): every lane emits one output
    float y = fmaf((float)aco[0], CHEAD, bov);
    if (l15 >= 8) y = __expf(fminf(fmaxf(y, -20.0f), 2.0f));
    out[((size_t)(tau - 1) * 256 + r0 + l4) * 16 + l15] = y;
  };

  f16 gva[3], gvb[3];
#pragma unroll
  for (int g = 0; g < 3; ++g) gva[g] = gp0[g * 512];

  auto step = [&](int cur, int nxt, f16 (&gv)[3], f16 (&gvn)[3],
                  const f16* gpn, int tt) {
    if ((tt & 7) == 0 && tt > 0) {
      if (wave < 8) head_tau(tt - 7 + wave);
      asm volatile("s_waitcnt lgkmcnt(0)\n\ts_barrier" ::: "memory");
    }
#pragma unroll
    for (int g = 0; g < 3; ++g) gvn[g] = gpn[g * 512];

    // kt-major: 3 independent acc chains interleaved (dep distance 3)
    i32x4 acc0 = {}, acc1 = {}, acc2 = {};
#pragma unroll
    for (int kt = 0; kt < 4; ++kt) {
      i32x4 a = *reinterpret_cast<const i32x4*>(ha + cur + kt * 1024 + lane * 16);
      acc0 = __builtin_amdgcn_mfma_i32_16x16x64_i8(a, whq[0][kt], acc0, 0, 0, 0);
      acc1 = __builtin_amdgcn_mfma_i32_16x16x64_i8(a, whq[1][kt], acc1, 0, 0, 0);
      acc2 = __builtin_amdgcn_mfma_i32_16x16x64_i8(a, whq[2][kt], acc2, 0, 0, 0);
    }

    // elementwise GRU: ONE h-value per thread (acc[0] = tile row 4*l4)
    {
      float pr = fmaf((float)acc0[0], CS, (float)gv[0]);
      float pz = fmaf((float)acc1[0], CS, (float)gv[1]);
      float pnh = fmaf((float)acc2[0], CS, bh128);
      float rg = sigm_s(pr);
      float zg = sigm_s(pz);
      float ng = tanh_s(fmaf(rg, pnh, (float)gv[2]));
      float h = ng + zg * (hcur - ng);
      hcur = h;
      float m = fmaf(h, 127.0f, FMAGIC);
      int hq = __builtin_bit_cast(int, m) - IMAGIC;
      ha[nxt + wrb] = (char)hq;
    }
    asm volatile("s_waitcnt lgkmcnt(0)\n\ts_barrier" ::: "memory");
  };

  for (int t = 0; t < 512; t += 2) {
    const f16* gp1 = gp0 + (size_t)(t + 1) * 196608;
    const f16* gp2 = gp0 + (size_t)(t + 2 <= 511 ? t + 2 : 511) * 196608;
    step((t & 7) * 4096, ((t + 1) & 7) * 4096, gva, gvb, gp1, t);
    step(((t + 1) & 7) * 4096, ((t + 2) & 7) * 4096, gvb, gva, gp2, t + 1);
  }

  if (wave < 8) head_tau(505 + wave);
}

extern "C" void kernel_launch(void* const* d_in, const int* in_sizes, int n_in,
                              void* d_out, int out_size, void* d_ws, size_t ws_size,
                              hipStream_t stream) {
  const float* x      = (const float*)d_in[0];
  const float* carry0 = (const float*)d_in[1];
  const float* Wi     = (const float*)d_in[2];
  const float* bi     = (const float*)d_in[3];
  const float* Wh     = (const float*)d_in[4];
  const float* bhn    = (const float*)d_in[5];
  const float* Wo     = (const float*)d_in[6];
  const float* bo     = (const float*)d_in[7];
  float* out = (float*)d_out;

  f16* gx  = (f16*)d_ws;                        // 512*256*768 f16 = 192 MiB
  f16* WiT = gx + (size_t)512 * 256 * 768;      // 768*256 f16 = 384 KiB
  f16* xh  = WiT + (size_t)768 * 256;           // 512*256*256 f16 = 64 MiB

  const size_t need = ((size_t)512 * 256 * 768 + (size_t)768 * 256 +
                       (size_t)512 * 256 * 256) * sizeof(f16);

  k_prep_wit<<<dim3(24, 8), dim3(32, 8), 0, stream>>>(Wi, WiT);
  if (ws_size >= need) {
    k_x16<<<dim3(2048), dim3(256), 0, stream>>>(x, xh);
    k_gemm_gx16<<<dim3(6, 1024), dim3(256), 0, stream>>>(xh, WiT, bi, gx);
  } else {
    k_gemm_gx<<<dim3(6, 1024), dim3(256), 0, stream>>>(x, WiT, bi, gx);
  }
  k_scan<<<dim3(64), dim3(1024), 0, stream>>>(carry0, Wh, bhn, gx, Wo, bo, out);
}